// Round 1
// baseline (891.206 us; speedup 1.0000x reference)
//
#include <hip/hip_runtime.h>
#include <hip/hip_bf16.h>

#define HW 3136
#define NPOS (8 * HW)

// ---------------------------------------------------------------------------
// Generic fp32 GEMM: Out[b][o][p] = sum_c W[o][c] * In[b][c][p] + bias[o]
// M=128 (o), K=128 (c), N=3136 (p) per batch; grid (98, 4), block 256.
// ---------------------------------------------------------------------------
__global__ __launch_bounds__(256) void gemm128_kernel(
    const float* __restrict__ In, const float* __restrict__ Wt,
    const float* __restrict__ bias, float* __restrict__ Out) {
  __shared__ float Ws[32][132];  // [c][o], pad keeps float4 align + banks spread
  __shared__ float Is[32][36];   // [c][p]
  int b = blockIdx.y;
  int pbase = blockIdx.x * 32;
  int t = threadIdx.x;
  int tx = t & 7, ty = t >> 3;
  int px = tx * 4, oy = ty * 4;
  const float* inb = In + (size_t)b * (128 * (size_t)HW);
  float acc[4][4] = {};
  for (int c0 = 0; c0 < 128; c0 += 32) {
    #pragma unroll
    for (int k = 0; k < 4; ++k) {
      int i4 = t + k * 256;            // 0..1023
      int o = i4 >> 3;                 // 0..127
      int cq = (i4 & 7) << 2;          // 0,4,...,28
      float4 wv = *(const float4*)&Wt[o * 128 + c0 + cq];
      Ws[cq + 0][o] = wv.x; Ws[cq + 1][o] = wv.y;
      Ws[cq + 2][o] = wv.z; Ws[cq + 3][o] = wv.w;
      int c = i4 >> 5, p = i4 & 31;    // 32x32 input tile
      Is[c][p] = inb[(size_t)(c0 + c) * HW + pbase + p];
    }
    __syncthreads();
    #pragma unroll
    for (int cc = 0; cc < 32; ++cc) {
      float4 w4 = *(const float4*)&Ws[cc][oy];
      float4 p4 = *(const float4*)&Is[cc][px];
      float wa[4] = {w4.x, w4.y, w4.z, w4.w};
      float ia[4] = {p4.x, p4.y, p4.z, p4.w};
      #pragma unroll
      for (int i = 0; i < 4; ++i)
        #pragma unroll
        for (int j = 0; j < 4; ++j)
          acc[i][j] += wa[i] * ia[j];
    }
    __syncthreads();
  }
  size_t ob = (size_t)b * (128 * (size_t)HW);
  #pragma unroll
  for (int i = 0; i < 4; ++i) {
    float bo = bias[oy + i];
    float4 r;
    r.x = acc[i][0] + bo; r.y = acc[i][1] + bo;
    r.z = acc[i][2] + bo; r.w = acc[i][3] + bo;
    *(float4*)&Out[ob + (size_t)(oy + i) * HW + pbase + px] = r;
  }
}

// ---------------------------------------------------------------------------
// Offset branch: depthwise 7x7 conv + LN(C) + GELU(exact) + 1x1 -> tanh ->
// pixel-space sample coords (gx, gy). grid (8, 56), block 64 (one wave/row).
// ---------------------------------------------------------------------------
__global__ __launch_bounds__(64) void offset_kernel(
    const float* __restrict__ q, const float* __restrict__ dw_w,
    const float* __restrict__ dw_b, const float* __restrict__ ln_g,
    const float* __restrict__ ln_b, const float* __restrict__ off_w,
    float* __restrict__ pos) {
  __shared__ float vs[64][65];  // [c][w]
  int bg = blockIdx.x, h = blockIdx.y;
  int w = threadIdx.x;  // 0..63, valid < 56 (extra lanes compute garbage, unstored)
  int b = bg >> 1, g = bg & 1;
  const float* qb = q + ((size_t)b * 128 + (size_t)g * 64) * HW;
  float sum = 0.f;
  #pragma unroll 2
  for (int c = 0; c < 64; ++c) {
    float acc = dw_b[c];
    const float* qc = qb + (size_t)c * HW;
    const float* wc = dw_w + c * 49;
    #pragma unroll
    for (int ky = 0; ky < 7; ++ky) {
      int y = h + ky - 3;
      if (y >= 0 && y < 56) {
        #pragma unroll
        for (int kx = 0; kx < 7; ++kx) {
          int xx = w + kx - 3;
          if (xx >= 0 && xx < 56)
            acc += qc[y * 56 + xx] * wc[ky * 7 + kx];
        }
      }
    }
    vs[c][w] = acc;
    sum += acc;
  }
  float mu = sum * 0.015625f;
  float var = 0.f;
  #pragma unroll 4
  for (int c = 0; c < 64; ++c) { float d = vs[c][w] - mu; var += d * d; }
  var *= 0.015625f;
  float rstd = rsqrtf(var + 1e-5f);
  float oy = 0.f, ox = 0.f;
  #pragma unroll 4
  for (int c = 0; c < 64; ++c) {
    float hn = (vs[c][w] - mu) * rstd * ln_g[c] + ln_b[c];
    hn = 0.5f * hn * (1.f + erff(hn * 0.70710678118654752f));
    oy += off_w[c] * hn;
    ox += off_w[64 + c] * hn;
  }
  float py = tanhf(oy) * (2.0f / 56.f) + ((h + 0.5f) * (2.f / 56.f) - 1.f);
  float px = tanhf(ox) * (2.0f / 56.f) + ((w + 0.5f) * (2.f / 56.f) - 1.f);
  if (w < 56) {
    int idx = bg * HW + h * 56 + w;
    pos[idx * 2 + 0] = (px + 1.f) * 0.5f * 55.f;  // gx in pixels
    pos[idx * 2 + 1] = (py + 1.f) * 0.5f * 55.f;  // gy in pixels
  }
}

// ---------------------------------------------------------------------------
// Bilinear grid sample (align_corners=True, zero padding).
// One thread per (bg, position); loop over 64 channels. grid 98, block 256.
// ---------------------------------------------------------------------------
__global__ __launch_bounds__(256) void sample_kernel(
    const float* __restrict__ x, const float* __restrict__ pos,
    float* __restrict__ xs) {
  int p = blockIdx.x * 256 + threadIdx.x;  // 0..25087
  int bg = p / HW, pp = p % HW;
  int b = bg >> 1, g = bg & 1;
  float gx = pos[2 * p], gy = pos[2 * p + 1];
  float x0f = floorf(gx), y0f = floorf(gy);
  float wx1 = gx - x0f, wx0 = 1.f - wx1;
  float wy1 = gy - y0f, wy0 = 1.f - wy1;
  int x0 = (int)x0f, y0 = (int)y0f;
  int x1 = x0 + 1, y1 = y0 + 1;
  float vx0 = (x0 >= 0 && x0 < 56) ? 1.f : 0.f;
  float vx1 = (x1 >= 0 && x1 < 56) ? 1.f : 0.f;
  float vy0 = (y0 >= 0 && y0 < 56) ? 1.f : 0.f;
  float vy1 = (y1 >= 0 && y1 < 56) ? 1.f : 0.f;
  int xc0 = min(max(x0, 0), 55), xc1 = min(max(x1, 0), 55);
  int yc0 = min(max(y0, 0), 55), yc1 = min(max(y1, 0), 55);
  float w00 = wx0 * wy0 * vx0 * vy0, w10 = wx1 * wy0 * vx1 * vy0;
  float w01 = wx0 * wy1 * vx0 * vy1, w11 = wx1 * wy1 * vx1 * vy1;
  int i00 = yc0 * 56 + xc0, i10 = yc0 * 56 + xc1;
  int i01 = yc1 * 56 + xc0, i11 = yc1 * 56 + xc1;
  const float* xb = x + ((size_t)b * 128 + (size_t)g * 64) * HW;
  float* ob = xs + ((size_t)b * 128 + (size_t)g * 64) * HW + pp;
  #pragma unroll 4
  for (int c = 0; c < 64; ++c) {
    const float* xc = xb + (size_t)c * HW;
    ob[(size_t)c * HW] = w00 * xc[i00] + w10 * xc[i10] + w01 * xc[i01] + w11 * xc[i11];
  }
}

// ---------------------------------------------------------------------------
// Flash attention fp32. grid (49, 16): (q-tile of 64 rows, b*4+head).
// 256 threads: thread t -> row r = t>>2, quad = t&3.
// S phase: each thread computes 16 logits (its quad's j range) over 32 ch.
// PV phase: each thread accumulates its quad's 8 channels over all 64 j.
// Online softmax state (m, l) per row, kept consistent across the 4 quads.
// ---------------------------------------------------------------------------
__global__ __launch_bounds__(256) void attn_kernel(
    const float* __restrict__ qb, const float* __restrict__ kbuf,
    const float* __restrict__ vbuf, float* __restrict__ ob) {
  __shared__ float Ks[32][64];   // [c][j]
  __shared__ float Vs[64][36];   // [j][c] transposed, padded
  __shared__ float Ps[64][68];   // [r][j] padded
  int bh = blockIdx.y;
  int b = bh >> 2, hd = bh & 3;
  int qbase = blockIdx.x * 64;
  int t = threadIdx.x;
  int r = t >> 2, quad = t & 3;
  size_t base = ((size_t)b * 128 + (size_t)hd * 32) * HW;
  const float* Q = qb + base;
  const float* K = kbuf + base;
  const float* V = vbuf + base;
  float qreg[32];
  #pragma unroll
  for (int c = 0; c < 32; ++c) qreg[c] = Q[(size_t)c * HW + qbase + r];
  float acc[8] = {};
  float m = -1e30f, l = 0.f;
  const float scale = 0.17677669529663687f;  // 1/sqrt(32)
  for (int kb0 = 0; kb0 < HW; kb0 += 64) {
    #pragma unroll
    for (int k = 0; k < 8; ++k) {
      int i = t + k * 256;
      int c = i >> 6, j = i & 63;
      Ks[c][j] = K[(size_t)c * HW + kb0 + j];
      Vs[j][c] = V[(size_t)c * HW + kb0 + j];
    }
    __syncthreads();
    float s[16];
    #pragma unroll
    for (int jj = 0; jj < 16; ++jj) s[jj] = 0.f;
    #pragma unroll
    for (int c = 0; c < 32; ++c) {
      float qv = qreg[c];
      const float* kr = &Ks[c][quad * 16];
      float4 k0 = *(const float4*)(kr);
      float4 k1 = *(const float4*)(kr + 4);
      float4 k2 = *(const float4*)(kr + 8);
      float4 k3 = *(const float4*)(kr + 12);
      s[0]  += qv * k0.x; s[1]  += qv * k0.y; s[2]  += qv * k0.z; s[3]  += qv * k0.w;
      s[4]  += qv * k1.x; s[5]  += qv * k1.y; s[6]  += qv * k1.z; s[7]  += qv * k1.w;
      s[8]  += qv * k2.x; s[9]  += qv * k2.y; s[10] += qv * k2.z; s[11] += qv * k2.w;
      s[12] += qv * k3.x; s[13] += qv * k3.y; s[14] += qv * k3.z; s[15] += qv * k3.w;
    }
    float cm = -1e30f;
    #pragma unroll
    for (int jj = 0; jj < 16; ++jj) { s[jj] *= scale; cm = fmaxf(cm, s[jj]); }
    cm = fmaxf(cm, __shfl_xor(cm, 1));
    cm = fmaxf(cm, __shfl_xor(cm, 2));
    float mn = fmaxf(m, cm);
    float fsc = __expf(m - mn);
    m = mn;
    #pragma unroll
    for (int i = 0; i < 8; ++i) acc[i] *= fsc;
    l *= fsc;
    float psum = 0.f;
    #pragma unroll
    for (int jj = 0; jj < 16; ++jj) {
      float p = __expf(s[jj] - mn);
      psum += p;
      Ps[r][quad * 16 + jj] = p;
    }
    l += psum;
    // Ps row r written/read entirely within one wave (lanes 4r..4r+3):
    // per-wave in-order LDS => no barrier needed before reading.
    #pragma unroll 4
    for (int j4 = 0; j4 < 16; ++j4) {
      float4 pv = *(const float4*)&Ps[r][j4 * 4];
      float pvv[4] = {pv.x, pv.y, pv.z, pv.w};
      #pragma unroll
      for (int u = 0; u < 4; ++u) {
        int j = j4 * 4 + u;
        const float* vr = &Vs[j][quad * 8];
        float4 v0 = *(const float4*)(vr);
        float4 v1 = *(const float4*)(vr + 4);
        float pu = pvv[u];
        acc[0] += pu * v0.x; acc[1] += pu * v0.y;
        acc[2] += pu * v0.z; acc[3] += pu * v0.w;
        acc[4] += pu * v1.x; acc[5] += pu * v1.y;
        acc[6] += pu * v1.z; acc[7] += pu * v1.w;
      }
    }
    __syncthreads();
  }
  float lt = l + __shfl_xor(l, 1);
  lt += __shfl_xor(lt, 2);
  float inv = 1.f / lt;
  float* O = ob + base + qbase + r;
  #pragma unroll
  for (int i = 0; i < 8; ++i)
    O[(size_t)(quad * 8 + i) * HW] = acc[i] * inv;
}

// ---------------------------------------------------------------------------
extern "C" void kernel_launch(void* const* d_in, const int* in_sizes, int n_in,
                              void* d_out, int out_size, void* d_ws, size_t ws_size,
                              hipStream_t stream) {
  const float* x    = (const float*)d_in[0];
  const float* dw_w = (const float*)d_in[1];
  const float* dw_b = (const float*)d_in[2];
  const float* ln_g = (const float*)d_in[3];
  const float* ln_b = (const float*)d_in[4];
  const float* offw = (const float*)d_in[5];
  const float* q_w  = (const float*)d_in[6];
  const float* q_b  = (const float*)d_in[7];
  const float* k_w  = (const float*)d_in[8];
  const float* k_b  = (const float*)d_in[9];
  const float* v_w  = (const float*)d_in[10];
  const float* v_b  = (const float*)d_in[11];
  const float* o_w  = (const float*)d_in[12];
  const float* o_b  = (const float*)d_in[13];

  float* ws  = (float*)d_ws;
  float* q   = ws;                  // 4*128*3136 = 1605632 floats
  float* xs  = q  + 1605632;
  float* kb  = xs + 1605632;
  float* vb  = kb + 1605632;
  float* ao  = vb + 1605632;
  float* pos = ao + 1605632;        // 8*3136*2 = 50176 floats
  float* out = (float*)d_out;

  dim3 gg(98, 4);
  gemm128_kernel<<<gg, 256, 0, stream>>>(x, q_w, q_b, q);
  offset_kernel<<<dim3(8, 56), 64, 0, stream>>>(q, dw_w, dw_b, ln_g, ln_b, offw, pos);
  sample_kernel<<<dim3(98), 256, 0, stream>>>(x, pos, xs);
  gemm128_kernel<<<gg, 256, 0, stream>>>(xs, k_w, k_b, kb);
  gemm128_kernel<<<gg, 256, 0, stream>>>(xs, v_w, v_b, vb);
  attn_kernel<<<dim3(49, 16), 256, 0, stream>>>(q, kb, vb, ao);
  gemm128_kernel<<<gg, 256, 0, stream>>>(ao, o_w, o_b, out);
}

// Round 2
// 418.605 us; speedup vs baseline: 2.1290x; 2.1290x over previous
//
#include <hip/hip_runtime.h>
#include <hip/hip_bf16.h>

#define HW 3136

typedef short s16x8 __attribute__((ext_vector_type(8)));
typedef float f32x4 __attribute__((ext_vector_type(4)));
typedef unsigned short us4 __attribute__((ext_vector_type(4)));

__device__ inline unsigned short f2bf(float f) {
  union { float f; unsigned int u; } v; v.f = f;
  unsigned int r = v.u + 0x7fff + ((v.u >> 16) & 1);
  return (unsigned short)(r >> 16);
}

// ---------------------------------------------------------------------------
// fp32 GEMM: Out[b][o][p] = sum_c W[o][c] * In[b][c][p] + bias[o]
// MODE: 0 = f32 out only, 1 = bf16 out only, 2 = both.
// ---------------------------------------------------------------------------
template <int MODE>
__global__ __launch_bounds__(256) void gemm128_kernel(
    const float* __restrict__ In, const float* __restrict__ Wt,
    const float* __restrict__ bias, float* __restrict__ Outf,
    unsigned short* __restrict__ Outb) {
  __shared__ float Ws[32][132];
  __shared__ float Is[32][36];
  int b = blockIdx.y;
  int pbase = blockIdx.x * 32;
  int t = threadIdx.x;
  int tx = t & 7, ty = t >> 3;
  int px = tx * 4, oy = ty * 4;
  const float* inb = In + (size_t)b * (128 * (size_t)HW);
  float acc[4][4] = {};
  for (int c0 = 0; c0 < 128; c0 += 32) {
    #pragma unroll
    for (int k = 0; k < 4; ++k) {
      int i4 = t + k * 256;
      int o = i4 >> 3;
      int cq = (i4 & 7) << 2;
      float4 wv = *(const float4*)&Wt[o * 128 + c0 + cq];
      Ws[cq + 0][o] = wv.x; Ws[cq + 1][o] = wv.y;
      Ws[cq + 2][o] = wv.z; Ws[cq + 3][o] = wv.w;
      int c = i4 >> 5, p = i4 & 31;
      Is[c][p] = inb[(size_t)(c0 + c) * HW + pbase + p];
    }
    __syncthreads();
    #pragma unroll
    for (int cc = 0; cc < 32; ++cc) {
      float4 w4 = *(const float4*)&Ws[cc][oy];
      float4 p4 = *(const float4*)&Is[cc][px];
      float wa[4] = {w4.x, w4.y, w4.z, w4.w};
      float ia[4] = {p4.x, p4.y, p4.z, p4.w};
      #pragma unroll
      for (int i = 0; i < 4; ++i)
        #pragma unroll
        for (int j = 0; j < 4; ++j)
          acc[i][j] += wa[i] * ia[j];
    }
    __syncthreads();
  }
  size_t ob = (size_t)b * (128 * (size_t)HW);
  #pragma unroll
  for (int i = 0; i < 4; ++i) {
    float bo = bias[oy + i];
    float r0 = acc[i][0] + bo, r1 = acc[i][1] + bo;
    float r2 = acc[i][2] + bo, r3 = acc[i][3] + bo;
    size_t idx = ob + (size_t)(oy + i) * HW + pbase + px;
    if (MODE != 1) {
      float4 r; r.x = r0; r.y = r1; r.z = r2; r.w = r3;
      *(float4*)&Outf[idx] = r;
    }
    if (MODE >= 1) {
      us4 rb;
      rb[0] = f2bf(r0); rb[1] = f2bf(r1); rb[2] = f2bf(r2); rb[3] = f2bf(r3);
      *(us4*)&Outb[idx] = rb;
    }
  }
}

// ---------------------------------------------------------------------------
// Offset branch (unchanged, fp32).
// ---------------------------------------------------------------------------
__global__ __launch_bounds__(64) void offset_kernel(
    const float* __restrict__ q, const float* __restrict__ dw_w,
    const float* __restrict__ dw_b, const float* __restrict__ ln_g,
    const float* __restrict__ ln_b, const float* __restrict__ off_w,
    float* __restrict__ pos) {
  __shared__ float vs[64][65];
  int bg = blockIdx.x, h = blockIdx.y;
  int w = threadIdx.x;
  int b = bg >> 1, g = bg & 1;
  const float* qb = q + ((size_t)b * 128 + (size_t)g * 64) * HW;
  float sum = 0.f;
  #pragma unroll 2
  for (int c = 0; c < 64; ++c) {
    float acc = dw_b[c];
    const float* qc = qb + (size_t)c * HW;
    const float* wc = dw_w + c * 49;
    #pragma unroll
    for (int ky = 0; ky < 7; ++ky) {
      int y = h + ky - 3;
      if (y >= 0 && y < 56) {
        #pragma unroll
        for (int kx = 0; kx < 7; ++kx) {
          int xx = w + kx - 3;
          if (xx >= 0 && xx < 56)
            acc += qc[y * 56 + xx] * wc[ky * 7 + kx];
        }
      }
    }
    vs[c][w] = acc;
    sum += acc;
  }
  float mu = sum * 0.015625f;
  float var = 0.f;
  #pragma unroll 4
  for (int c = 0; c < 64; ++c) { float d = vs[c][w] - mu; var += d * d; }
  var *= 0.015625f;
  float rstd = rsqrtf(var + 1e-5f);
  float oy = 0.f, ox = 0.f;
  #pragma unroll 4
  for (int c = 0; c < 64; ++c) {
    float hn = (vs[c][w] - mu) * rstd * ln_g[c] + ln_b[c];
    hn = 0.5f * hn * (1.f + erff(hn * 0.70710678118654752f));
    oy += off_w[c] * hn;
    ox += off_w[64 + c] * hn;
  }
  float py = tanhf(oy) * (2.0f / 56.f) + ((h + 0.5f) * (2.f / 56.f) - 1.f);
  float px = tanhf(ox) * (2.0f / 56.f) + ((w + 0.5f) * (2.f / 56.f) - 1.f);
  if (w < 56) {
    int idx = bg * HW + h * 56 + w;
    pos[idx * 2 + 0] = (px + 1.f) * 0.5f * 55.f;
    pos[idx * 2 + 1] = (py + 1.f) * 0.5f * 55.f;
  }
}

// ---------------------------------------------------------------------------
// Bilinear grid sample (unchanged, fp32).
// ---------------------------------------------------------------------------
__global__ __launch_bounds__(256) void sample_kernel(
    const float* __restrict__ x, const float* __restrict__ pos,
    float* __restrict__ xs) {
  int p = blockIdx.x * 256 + threadIdx.x;
  int bg = p / HW, pp = p % HW;
  int b = bg >> 1, g = bg & 1;
  float gx = pos[2 * p], gy = pos[2 * p + 1];
  float x0f = floorf(gx), y0f = floorf(gy);
  float wx1 = gx - x0f, wx0 = 1.f - wx1;
  float wy1 = gy - y0f, wy0 = 1.f - wy1;
  int x0 = (int)x0f, y0 = (int)y0f;
  int x1 = x0 + 1, y1 = y0 + 1;
  float vx0 = (x0 >= 0 && x0 < 56) ? 1.f : 0.f;
  float vx1 = (x1 >= 0 && x1 < 56) ? 1.f : 0.f;
  float vy0 = (y0 >= 0 && y0 < 56) ? 1.f : 0.f;
  float vy1 = (y1 >= 0 && y1 < 56) ? 1.f : 0.f;
  int xc0 = min(max(x0, 0), 55), xc1 = min(max(x1, 0), 55);
  int yc0 = min(max(y0, 0), 55), yc1 = min(max(y1, 0), 55);
  float w00 = wx0 * wy0 * vx0 * vy0, w10 = wx1 * wy0 * vx1 * vy0;
  float w01 = wx0 * wy1 * vx0 * vy1, w11 = wx1 * wy1 * vx1 * vy1;
  int i00 = yc0 * 56 + xc0, i10 = yc0 * 56 + xc1;
  int i01 = yc1 * 56 + xc0, i11 = yc1 * 56 + xc1;
  const float* xb = x + ((size_t)b * 128 + (size_t)g * 64) * HW;
  float* ob = xs + ((size_t)b * 128 + (size_t)g * 64) * HW + pp;
  #pragma unroll 4
  for (int c = 0; c < 64; ++c) {
    const float* xc = xb + (size_t)c * HW;
    ob[(size_t)c * HW] = w00 * xc[i00] + w10 * xc[i10] + w01 * xc[i01] + w11 * xc[i11];
  }
}

// ---------------------------------------------------------------------------
// MFMA flash attention, bf16 inputs, fp32 accumulate.
// grid (49, 16): (q-tile of 64, b*4+head). 256 threads = 4 waves.
// Each wave owns 16 q-positions. K-loop in tiles of 64 kpos.
// S^T = K^T·Q  (4 MFMAs, K dim = 32 = head channels, one shot)
//   -> lane owns qpos = lane&15: softmax lane-local + shfl_xor(16,32).
// P -> per-wave LDS [16 q][64 kpos] bf16.
// O^T[ch][q] += V·P^T (4 MFMAs) -> rescale factor lane-local (col=q).
// ---------------------------------------------------------------------------
__global__ __launch_bounds__(256) void attn_mfma_kernel(
    const unsigned short* __restrict__ qbf, const unsigned short* __restrict__ kbf,
    const unsigned short* __restrict__ vbf, float* __restrict__ ob) {
  __shared__ __align__(16) unsigned short Klds[64][36];   // [kpos][ch] padded
  __shared__ __align__(16) unsigned short Plds[4][16][68]; // per-wave [q][kpos]
  int bh = blockIdx.y;
  int t = threadIdx.x;
  int w = t >> 6, l = t & 63;
  int lq = l & 15, h = l >> 4;
  size_t base = (size_t)bh * 32 * HW;
  int q0 = blockIdx.x * 64 + w * 16;

  union S8 { s16x8 v; long long q[2]; unsigned short u[8]; };

  // Q B-fragment: lane holds Q[ch = h*8+j][q0 + lq]
  S8 qf;
  #pragma unroll
  for (int j = 0; j < 8; ++j)
    qf.u[j] = qbf[base + (size_t)(h * 8 + j) * HW + q0 + lq];

  f32x4 oacc[2] = {{0.f, 0.f, 0.f, 0.f}, {0.f, 0.f, 0.f, 0.f}};
  float m = -1e30f, lsum = 0.f;
  const float scale = 0.17677669529663687f;

  for (int kb0 = 0; kb0 < HW; kb0 += 64) {
    // ---- stage K tile -> LDS transposed: Klds[kpos][ch] ----
    {
      int kp = t & 63;
      const unsigned short* kr = kbf + base + kb0 + kp;
      unsigned short tmp[8];
      #pragma unroll
      for (int j = 0; j < 8; ++j)
        tmp[j] = kr[(size_t)(8 * w + j) * HW];
      #pragma unroll
      for (int i = 0; i < 4; ++i) {
        unsigned int pk = (unsigned int)tmp[2 * i] | ((unsigned int)tmp[2 * i + 1] << 16);
        *(unsigned int*)&Klds[kp][8 * w + 2 * i] = pk;
      }
    }
    __syncthreads();

    // ---- S^T tiles: D[kpos][qpos], 4 MFMAs ----
    f32x4 st[4];
    #pragma unroll
    for (int tt = 0; tt < 4; ++tt) {
      S8 af;
      af.q[0] = *(const long long*)&Klds[tt * 16 + lq][h * 8];
      af.q[1] = *(const long long*)&Klds[tt * 16 + lq][h * 8 + 4];
      st[tt] = __builtin_amdgcn_mfma_f32_16x16x32_bf16(
          af.v, qf.v, (f32x4){0.f, 0.f, 0.f, 0.f}, 0, 0, 0);
    }

    // ---- online softmax (lane owns qpos = lq) ----
    float sv[16];
    float cm = -1e30f;
    #pragma unroll
    for (int tt = 0; tt < 4; ++tt)
      #pragma unroll
      for (int r = 0; r < 4; ++r) {
        float xv = st[tt][r] * scale;
        sv[tt * 4 + r] = xv;
        cm = fmaxf(cm, xv);
      }
    cm = fmaxf(cm, __shfl_xor(cm, 16));
    cm = fmaxf(cm, __shfl_xor(cm, 32));
    float mn = fmaxf(m, cm);
    float fsc = __expf(m - mn);
    m = mn;
    oacc[0] *= fsc;
    oacc[1] *= fsc;
    float ps = 0.f;
    unsigned short pb[16];
    #pragma unroll
    for (int i = 0; i < 16; ++i) {
      float p = __expf(sv[i] - mn);
      ps += p;
      pb[i] = f2bf(p);
    }
    ps += __shfl_xor(ps, 16);
    ps += __shfl_xor(ps, 32);
    lsum = lsum * fsc + ps;

    // ---- P -> per-wave LDS: Plds[w][q][kpos], kpos = tt*16 + 4h + r ----
    #pragma unroll
    for (int tt = 0; tt < 4; ++tt) {
      unsigned long long pk =
          (unsigned long long)pb[tt * 4] |
          ((unsigned long long)pb[tt * 4 + 1] << 16) |
          ((unsigned long long)pb[tt * 4 + 2] << 32) |
          ((unsigned long long)pb[tt * 4 + 3] << 48);
      *(unsigned long long*)&Plds[w][lq][tt * 16 + h * 4] = pk;
    }

    // ---- PV: D[ch][q] += V · P^T, 4 MFMAs ----
    #pragma unroll
    for (int c = 0; c < 2; ++c) {
      S8 pf;
      pf.q[0] = *(const long long*)&Plds[w][lq][c * 32 + h * 8];
      pf.q[1] = *(const long long*)&Plds[w][lq][c * 32 + h * 8 + 4];
      #pragma unroll
      for (int n = 0; n < 2; ++n) {
        const s16x8* vp = (const s16x8*)&vbf[base + (size_t)(n * 16 + lq) * HW +
                                             kb0 + c * 32 + h * 8];
        s16x8 vf = *vp;
        oacc[n] = __builtin_amdgcn_mfma_f32_16x16x32_bf16(vf, pf.v, oacc[n], 0, 0, 0);
      }
    }
    __syncthreads();
  }

  float inv = 1.f / lsum;
  #pragma unroll
  for (int n = 0; n < 2; ++n)
    #pragma unroll
    for (int r = 0; r < 4; ++r)
      ob[base + (size_t)(n * 16 + h * 4 + r) * HW + q0 + lq] = oacc[n][r] * inv;
}

// ---------------------------------------------------------------------------
extern "C" void kernel_launch(void* const* d_in, const int* in_sizes, int n_in,
                              void* d_out, int out_size, void* d_ws, size_t ws_size,
                              hipStream_t stream) {
  const float* x    = (const float*)d_in[0];
  const float* dw_w = (const float*)d_in[1];
  const float* dw_b = (const float*)d_in[2];
  const float* ln_g = (const float*)d_in[3];
  const float* ln_b = (const float*)d_in[4];
  const float* offw = (const float*)d_in[5];
  const float* q_w  = (const float*)d_in[6];
  const float* q_b  = (const float*)d_in[7];
  const float* k_w  = (const float*)d_in[8];
  const float* k_b  = (const float*)d_in[9];
  const float* v_w  = (const float*)d_in[10];
  const float* v_b  = (const float*)d_in[11];
  const float* o_w  = (const float*)d_in[12];
  const float* o_b  = (const float*)d_in[13];

  const size_t NE = 1605632;  // 4*128*3136
  float* ws  = (float*)d_ws;
  float* q   = ws;            // fp32 q (offset branch)
  float* xs  = q  + NE;       // sampled features fp32
  float* ao  = xs + NE;       // attention output fp32
  float* pos = ao + NE;       // 50176 floats
  unsigned short* qb = (unsigned short*)(pos + 50176);
  unsigned short* kb = qb + NE;
  unsigned short* vb = kb + NE;
  float* out = (float*)d_out;

  dim3 gg(98, 4);
  gemm128_kernel<2><<<gg, 256, 0, stream>>>(x, q_w, q_b, q, qb);
  offset_kernel<<<dim3(8, 56), 64, 0, stream>>>(q, dw_w, dw_b, ln_g, ln_b, offw, pos);
  sample_kernel<<<dim3(98), 256, 0, stream>>>(x, pos, xs);
  gemm128_kernel<1><<<gg, 256, 0, stream>>>(xs, k_w, k_b, nullptr, kb);
  gemm128_kernel<1><<<gg, 256, 0, stream>>>(xs, v_w, v_b, nullptr, vb);
  attn_mfma_kernel<<<dim3(49, 16), 256, 0, stream>>>(qb, kb, vb, ao);
  gemm128_kernel<0><<<gg, 256, 0, stream>>>(ao, o_w, o_b, out, nullptr);
}

// Round 3
// 266.847 us; speedup vs baseline: 3.3398x; 1.5687x over previous
//
#include <hip/hip_runtime.h>
#include <hip/hip_bf16.h>

#define HW 3136

typedef short s16x8 __attribute__((ext_vector_type(8)));
typedef float f32x4 __attribute__((ext_vector_type(4)));
typedef unsigned short us4 __attribute__((ext_vector_type(4)));

__device__ inline unsigned short f2bf(float f) {
  union { float f; unsigned int u; } v; v.f = f;
  unsigned int r = v.u + 0x7fff + ((v.u >> 16) & 1);
  return (unsigned short)(r >> 16);
}

// ---------------------------------------------------------------------------
// fp32 GEMM: Out[b][o][p] = sum_c W[o][c] * In[b][c][p] + bias[o]
// MODE: 0 = f32 out only, 1 = bf16 out only, 2 = both.
// ---------------------------------------------------------------------------
template <int MODE>
__global__ __launch_bounds__(256) void gemm128_kernel(
    const float* __restrict__ In, const float* __restrict__ Wt,
    const float* __restrict__ bias, float* __restrict__ Outf,
    unsigned short* __restrict__ Outb) {
  __shared__ float Ws[32][132];
  __shared__ float Is[32][36];
  int b = blockIdx.y;
  int pbase = blockIdx.x * 32;
  int t = threadIdx.x;
  int tx = t & 7, ty = t >> 3;
  int px = tx * 4, oy = ty * 4;
  const float* inb = In + (size_t)b * (128 * (size_t)HW);
  float acc[4][4] = {};
  for (int c0 = 0; c0 < 128; c0 += 32) {
    #pragma unroll
    for (int k = 0; k < 4; ++k) {
      int i4 = t + k * 256;
      int o = i4 >> 3;
      int cq = (i4 & 7) << 2;
      float4 wv = *(const float4*)&Wt[o * 128 + c0 + cq];
      Ws[cq + 0][o] = wv.x; Ws[cq + 1][o] = wv.y;
      Ws[cq + 2][o] = wv.z; Ws[cq + 3][o] = wv.w;
      int c = i4 >> 5, p = i4 & 31;
      Is[c][p] = inb[(size_t)(c0 + c) * HW + pbase + p];
    }
    __syncthreads();
    #pragma unroll
    for (int cc = 0; cc < 32; ++cc) {
      float4 w4 = *(const float4*)&Ws[cc][oy];
      float4 p4 = *(const float4*)&Is[cc][px];
      float wa[4] = {w4.x, w4.y, w4.z, w4.w};
      float ia[4] = {p4.x, p4.y, p4.z, p4.w};
      #pragma unroll
      for (int i = 0; i < 4; ++i)
        #pragma unroll
        for (int j = 0; j < 4; ++j)
          acc[i][j] += wa[i] * ia[j];
    }
    __syncthreads();
  }
  size_t ob = (size_t)b * (128 * (size_t)HW);
  #pragma unroll
  for (int i = 0; i < 4; ++i) {
    float bo = bias[oy + i];
    float r0 = acc[i][0] + bo, r1 = acc[i][1] + bo;
    float r2 = acc[i][2] + bo, r3 = acc[i][3] + bo;
    size_t idx = ob + (size_t)(oy + i) * HW + pbase + px;
    if (MODE != 1) {
      float4 r; r.x = r0; r.y = r1; r.z = r2; r.w = r3;
      *(float4*)&Outf[idx] = r;
    }
    if (MODE >= 1) {
      us4 rb;
      rb[0] = f2bf(r0); rb[1] = f2bf(r1); rb[2] = f2bf(r2); rb[3] = f2bf(r3);
      *(us4*)&Outb[idx] = rb;
    }
  }
}

// ---------------------------------------------------------------------------
// Offset branch, re-parallelized: block 256 = 4 waves per (bg, h-row).
// thread (cq = t>>6, w = t&63): depthwise 7x7 conv for 16 channels at col w.
// LN stats by wave 0 (two-pass, per column); GELU + 1x1 as 4-wave partials.
// ---------------------------------------------------------------------------
__global__ __launch_bounds__(256) void offset_kernel(
    const float* __restrict__ q, const float* __restrict__ dw_w,
    const float* __restrict__ dw_b, const float* __restrict__ ln_g,
    const float* __restrict__ ln_b, const float* __restrict__ off_w,
    float* __restrict__ pos) {
  __shared__ float vs[64][65];       // [c][w]
  __shared__ float mu_s[64], rs_s[64];
  __shared__ float part[4][64][2];
  int bg = blockIdx.x, h = blockIdx.y;
  int t = threadIdx.x;
  int w = t & 63;       // valid < 56
  int cq = t >> 6;      // 0..3
  int b = bg >> 1, g = bg & 1;
  const float* qb = q + ((size_t)b * 128 + (size_t)g * 64) * HW;

  #pragma unroll
  for (int i = 0; i < 16; ++i) {
    int c = cq * 16 + i;
    float acc = dw_b[c];
    const float* qc = qb + (size_t)c * HW;
    const float* wc = dw_w + c * 49;
    #pragma unroll
    for (int ky = 0; ky < 7; ++ky) {
      int y = h + ky - 3;
      if (y >= 0 && y < 56) {
        #pragma unroll
        for (int kx = 0; kx < 7; ++kx) {
          int xx = w + kx - 3;
          if (xx >= 0 && xx < 56)
            acc += qc[y * 56 + xx] * wc[ky * 7 + kx];
        }
      }
    }
    vs[c][w] = acc;
  }
  __syncthreads();

  if (cq == 0) {
    float sum = 0.f;
    #pragma unroll 8
    for (int c = 0; c < 64; ++c) sum += vs[c][w];
    float mu = sum * 0.015625f;
    float var = 0.f;
    #pragma unroll 8
    for (int c = 0; c < 64; ++c) { float d = vs[c][w] - mu; var += d * d; }
    mu_s[w] = mu;
    rs_s[w] = rsqrtf(var * 0.015625f + 1e-5f);
  }
  __syncthreads();

  {
    float mu = mu_s[w], rstd = rs_s[w];
    float oy = 0.f, ox = 0.f;
    #pragma unroll
    for (int i = 0; i < 16; ++i) {
      int c = cq * 16 + i;
      float hn = (vs[c][w] - mu) * rstd * ln_g[c] + ln_b[c];
      hn = 0.5f * hn * (1.f + erff(hn * 0.70710678118654752f));
      oy += off_w[c] * hn;
      ox += off_w[64 + c] * hn;
    }
    part[cq][w][0] = oy;
    part[cq][w][1] = ox;
  }
  __syncthreads();

  if (cq == 0 && w < 56) {
    float oy = part[0][w][0] + part[1][w][0] + part[2][w][0] + part[3][w][0];
    float ox = part[0][w][1] + part[1][w][1] + part[2][w][1] + part[3][w][1];
    float py = tanhf(oy) * (2.0f / 56.f) + ((h + 0.5f) * (2.f / 56.f) - 1.f);
    float px = tanhf(ox) * (2.0f / 56.f) + ((w + 0.5f) * (2.f / 56.f) - 1.f);
    int idx = bg * HW + h * 56 + w;
    pos[idx * 2 + 0] = (px + 1.f) * 0.5f * 55.f;
    pos[idx * 2 + 1] = (py + 1.f) * 0.5f * 55.f;
  }
}

// ---------------------------------------------------------------------------
// Bilinear grid sample (unchanged, fp32).
// ---------------------------------------------------------------------------
__global__ __launch_bounds__(256) void sample_kernel(
    const float* __restrict__ x, const float* __restrict__ pos,
    float* __restrict__ xs) {
  int p = blockIdx.x * 256 + threadIdx.x;
  int bg = p / HW, pp = p % HW;
  int b = bg >> 1, g = bg & 1;
  float gx = pos[2 * p], gy = pos[2 * p + 1];
  float x0f = floorf(gx), y0f = floorf(gy);
  float wx1 = gx - x0f, wx0 = 1.f - wx1;
  float wy1 = gy - y0f, wy0 = 1.f - wy1;
  int x0 = (int)x0f, y0 = (int)y0f;
  int x1 = x0 + 1, y1 = y0 + 1;
  float vx0 = (x0 >= 0 && x0 < 56) ? 1.f : 0.f;
  float vx1 = (x1 >= 0 && x1 < 56) ? 1.f : 0.f;
  float vy0 = (y0 >= 0 && y0 < 56) ? 1.f : 0.f;
  float vy1 = (y1 >= 0 && y1 < 56) ? 1.f : 0.f;
  int xc0 = min(max(x0, 0), 55), xc1 = min(max(x1, 0), 55);
  int yc0 = min(max(y0, 0), 55), yc1 = min(max(y1, 0), 55);
  float w00 = wx0 * wy0 * vx0 * vy0, w10 = wx1 * wy0 * vx1 * vy0;
  float w01 = wx0 * wy1 * vx0 * vy1, w11 = wx1 * wy1 * vx1 * vy1;
  int i00 = yc0 * 56 + xc0, i10 = yc0 * 56 + xc1;
  int i01 = yc1 * 56 + xc0, i11 = yc1 * 56 + xc1;
  const float* xb = x + ((size_t)b * 128 + (size_t)g * 64) * HW;
  float* ob = xs + ((size_t)b * 128 + (size_t)g * 64) * HW + pp;
  #pragma unroll 4
  for (int c = 0; c < 64; ++c) {
    const float* xc = xb + (size_t)c * HW;
    ob[(size_t)c * HW] = w00 * xc[i00] + w10 * xc[i10] + w01 * xc[i01] + w11 * xc[i11];
  }
}

// ---------------------------------------------------------------------------
// MFMA flash attention (unchanged from round 2).
// ---------------------------------------------------------------------------
__global__ __launch_bounds__(256) void attn_mfma_kernel(
    const unsigned short* __restrict__ qbf, const unsigned short* __restrict__ kbf,
    const unsigned short* __restrict__ vbf, float* __restrict__ ob) {
  __shared__ __align__(16) unsigned short Klds[64][36];
  __shared__ __align__(16) unsigned short Plds[4][16][68];
  int bh = blockIdx.y;
  int t = threadIdx.x;
  int w = t >> 6, l = t & 63;
  int lq = l & 15, h = l >> 4;
  size_t base = (size_t)bh * 32 * HW;
  int q0 = blockIdx.x * 64 + w * 16;

  union S8 { s16x8 v; long long q[2]; unsigned short u[8]; };

  S8 qf;
  #pragma unroll
  for (int j = 0; j < 8; ++j)
    qf.u[j] = qbf[base + (size_t)(h * 8 + j) * HW + q0 + lq];

  f32x4 oacc[2] = {{0.f, 0.f, 0.f, 0.f}, {0.f, 0.f, 0.f, 0.f}};
  float m = -1e30f, lsum = 0.f;
  const float scale = 0.17677669529663687f;

  for (int kb0 = 0; kb0 < HW; kb0 += 64) {
    {
      int kp = t & 63;
      const unsigned short* kr = kbf + base + kb0 + kp;
      unsigned short tmp[8];
      #pragma unroll
      for (int j = 0; j < 8; ++j)
        tmp[j] = kr[(size_t)(8 * w + j) * HW];
      #pragma unroll
      for (int i = 0; i < 4; ++i) {
        unsigned int pk = (unsigned int)tmp[2 * i] | ((unsigned int)tmp[2 * i + 1] << 16);
        *(unsigned int*)&Klds[kp][8 * w + 2 * i] = pk;
      }
    }
    __syncthreads();

    f32x4 st[4];
    #pragma unroll
    for (int tt = 0; tt < 4; ++tt) {
      S8 af;
      af.q[0] = *(const long long*)&Klds[tt * 16 + lq][h * 8];
      af.q[1] = *(const long long*)&Klds[tt * 16 + lq][h * 8 + 4];
      st[tt] = __builtin_amdgcn_mfma_f32_16x16x32_bf16(
          af.v, qf.v, (f32x4){0.f, 0.f, 0.f, 0.f}, 0, 0, 0);
    }

    float sv[16];
    float cm = -1e30f;
    #pragma unroll
    for (int tt = 0; tt < 4; ++tt)
      #pragma unroll
      for (int r = 0; r < 4; ++r) {
        float xv = st[tt][r] * scale;
        sv[tt * 4 + r] = xv;
        cm = fmaxf(cm, xv);
      }
    cm = fmaxf(cm, __shfl_xor(cm, 16));
    cm = fmaxf(cm, __shfl_xor(cm, 32));
    float mn = fmaxf(m, cm);
    float fsc = __expf(m - mn);
    m = mn;
    oacc[0] *= fsc;
    oacc[1] *= fsc;
    float ps = 0.f;
    unsigned short pb[16];
    #pragma unroll
    for (int i = 0; i < 16; ++i) {
      float p = __expf(sv[i] - mn);
      ps += p;
      pb[i] = f2bf(p);
    }
    ps += __shfl_xor(ps, 16);
    ps += __shfl_xor(ps, 32);
    lsum = lsum * fsc + ps;

    #pragma unroll
    for (int tt = 0; tt < 4; ++tt) {
      unsigned long long pk =
          (unsigned long long)pb[tt * 4] |
          ((unsigned long long)pb[tt * 4 + 1] << 16) |
          ((unsigned long long)pb[tt * 4 + 2] << 32) |
          ((unsigned long long)pb[tt * 4 + 3] << 48);
      *(unsigned long long*)&Plds[w][lq][tt * 16 + h * 4] = pk;
    }

    #pragma unroll
    for (int c = 0; c < 2; ++c) {
      S8 pf;
      pf.q[0] = *(const long long*)&Plds[w][lq][c * 32 + h * 8];
      pf.q[1] = *(const long long*)&Plds[w][lq][c * 32 + h * 8 + 4];
      #pragma unroll
      for (int n = 0; n < 2; ++n) {
        const s16x8* vp = (const s16x8*)&vbf[base + (size_t)(n * 16 + lq) * HW +
                                             kb0 + c * 32 + h * 8];
        s16x8 vf = *vp;
        oacc[n] = __builtin_amdgcn_mfma_f32_16x16x32_bf16(vf, pf.v, oacc[n], 0, 0, 0);
      }
    }
    __syncthreads();
  }

  float inv = 1.f / lsum;
  #pragma unroll
  for (int n = 0; n < 2; ++n)
    #pragma unroll
    for (int r = 0; r < 4; ++r)
      ob[base + (size_t)(n * 16 + h * 4 + r) * HW + q0 + lq] = oacc[n][r] * inv;
}

// ---------------------------------------------------------------------------
extern "C" void kernel_launch(void* const* d_in, const int* in_sizes, int n_in,
                              void* d_out, int out_size, void* d_ws, size_t ws_size,
                              hipStream_t stream) {
  const float* x    = (const float*)d_in[0];
  const float* dw_w = (const float*)d_in[1];
  const float* dw_b = (const float*)d_in[2];
  const float* ln_g = (const float*)d_in[3];
  const float* ln_b = (const float*)d_in[4];
  const float* offw = (const float*)d_in[5];
  const float* q_w  = (const float*)d_in[6];
  const float* q_b  = (const float*)d_in[7];
  const float* k_w  = (const float*)d_in[8];
  const float* k_b  = (const float*)d_in[9];
  const float* v_w  = (const float*)d_in[10];
  const float* v_b  = (const float*)d_in[11];
  const float* o_w  = (const float*)d_in[12];
  const float* o_b  = (const float*)d_in[13];

  const size_t NE = 1605632;  // 4*128*3136
  float* ws  = (float*)d_ws;
  float* q   = ws;            // fp32 q (offset branch)
  float* xs  = q  + NE;       // sampled features fp32
  float* ao  = xs + NE;       // attention output fp32
  float* pos = ao + NE;       // 50176 floats
  unsigned short* qb = (unsigned short*)(pos + 50176);
  unsigned short* kb = qb + NE;
  unsigned short* vb = kb + NE;
  float* out = (float*)d_out;

  dim3 gg(98, 4);
  gemm128_kernel<2><<<gg, 256, 0, stream>>>(x, q_w, q_b, q, qb);
  offset_kernel<<<dim3(8, 56), 256, 0, stream>>>(q, dw_w, dw_b, ln_g, ln_b, offw, pos);
  sample_kernel<<<dim3(98), 256, 0, stream>>>(x, pos, xs);
  gemm128_kernel<1><<<gg, 256, 0, stream>>>(xs, k_w, k_b, nullptr, kb);
  gemm128_kernel<1><<<gg, 256, 0, stream>>>(xs, v_w, v_b, nullptr, vb);
  attn_mfma_kernel<<<dim3(49, 16), 256, 0, stream>>>(qb, kb, vb, ao);
  gemm128_kernel<0><<<gg, 256, 0, stream>>>(ao, o_w, o_b, out, nullptr);
}